// Round 4
// baseline (4622.301 us; speedup 1.0000x reference)
//
#include <hip/hip_runtime.h>

#define NTH 640          // 10 waves, 1 block/CU (LDS-limited)
#define SPB 8            // samples per block
#define W66 66
#define PIX36 36
#define NPOS 18          // kx in 0..5, ky in 0..2
#define FEAT 2376        // 66*36
#define TT 256
#define NSAMP 16384
#define SROW 2380        // padded floats per sample in row buffers (36*66 + 4)

// ws float offsets
#define PACK_FLOATS (2 * NPOS * W66 * W66)    // 313632
#define F2_OFF   PACK_FLOATS                  // 648 float2
#define G2_OFF   (F2_OFF + 1296)              // 648 float2
#define FS_OFF   (G2_OFF + 1296)              // 18 float2 (pad to 72)
#define GI0_OFF  (FS_OFF + 72)

__constant__ float COS6[6] = {1.f, 0.5f, -0.5f, -1.f, -0.5f, 0.5f};
__constant__ float SIN6[6] = {0.f, 0.8660254037844386468f, 0.8660254037844386468f,
                              0.f, -0.8660254037844386468f, -0.8660254037844386468f};

__device__ __forceinline__ float gelu_f(float v) {
    return 0.5f * v * (1.f + erff(v * 0.70710678118654752440f));
}

__device__ __forceinline__ void load_row36(float* d, const float* p) {
    const float4* r = (const float4*)p;
    #pragma unroll
    for (int q = 0; q < 9; ++q) {
        float4 v = r[q];
        d[4*q] = v.x; d[4*q+1] = v.y; d[4*q+2] = v.z; d[4*q+3] = v.w;
    }
}
__device__ __forceinline__ void store_row36(float* p, const float* d) {
    float4* r = (float4*)p;
    #pragma unroll
    for (int q = 0; q < 9; ++q)
        r[q] = make_float4(d[4*q], d[4*q+1], d[4*q+2], d[4*q+3]);
}

// repack spectral weights into pack[L][p][i][o][{re,im}], p = kx*3+ky, kx 0..5
// and build DFT tables F2[p][k], G2[p][pix], Fsum2[p] in global ws.
extern "C" __global__ void repack_kernel(
    const float* __restrict__ w1r0, const float* __restrict__ w1i0,
    const float* __restrict__ w2r0, const float* __restrict__ w2i0,
    const float* __restrict__ w1r1, const float* __restrict__ w1i1,
    const float* __restrict__ w2r1, const float* __restrict__ w2i1,
    float* __restrict__ ws)
{
    int e = blockIdx.x * blockDim.x + threadIdx.x;
    const int TOT = 2 * NPOS * W66 * W66;
    if (e < TOT) {
        int L = e / (NPOS * W66 * W66);
        int r = e % (NPOS * W66 * W66);
        int p = r / (W66 * W66);
        int io = r % (W66 * W66);
        int i = io / W66, o = io % W66;
        int kx = p / 3, ky = p % 3;
        const float *wr, *wi;
        int kxw;
        if (L == 0) { if (kx < 3) { wr = w1r0; wi = w1i0; kxw = kx; } else { wr = w2r0; wi = w2i0; kxw = kx - 3; } }
        else        { if (kx < 3) { wr = w1r1; wi = w1i1; kxw = kx; } else { wr = w2r1; wi = w2i1; kxw = kx - 3; } }
        int src = ((i * W66 + o) * 3 + kxw) * 3 + ky;
        ws[(size_t)e * 2 + 0] = wr[src];
        ws[(size_t)e * 2 + 1] = wi[src];
    }
    if (e < NPOS * PIX36) {       // F2 and G2 tables
        int p = e / PIX36, k = e % PIX36;
        int kx = p / 3, ky = p % 3;
        int px = k / 6, py = k % 6;
        int m6 = (kx * px + ky * py) % 6;
        ws[F2_OFF + 2 * e + 0] = COS6[m6];
        ws[F2_OFF + 2 * e + 1] = -SIN6[m6];
        float ck = (ky == 0) ? (1.f / 36.f) : (1.f / 18.f);
        ws[G2_OFF + 2 * e + 0] = ck * COS6[m6];
        ws[G2_OFF + 2 * e + 1] = -ck * SIN6[m6];
    }
    if (e < NPOS) {               // Fsum2[p]
        int kx = e / 3, ky = e % 3;
        float sr = 0.f, si = 0.f;
        for (int k = 0; k < PIX36; ++k) {
            int m6 = (kx * (k / 6) + ky * (k % 6)) % 6;
            sr += COS6[m6]; si -= SIN6[m6];
        }
        ws[FS_OFF + 2 * e + 0] = sr;
        ws[FS_OFF + 2 * e + 1] = si;
    }
}

extern "C" __global__ void __launch_bounds__(NTH)
__attribute__((amdgpu_waves_per_eu(3, 3)))
fno_kernel(const float* __restrict__ X, const float* __restrict__ p_w,
           const float* __restrict__ p_b, const float* __restrict__ ws,
           const float* __restrict__ m0aw, const float* __restrict__ m0ab,
           const float* __restrict__ m0bw, const float* __restrict__ m0bb,
           const float* __restrict__ m1aw, const float* __restrict__ m1ab,
           const float* __restrict__ m1bw, const float* __restrict__ m1bb,
           const float* __restrict__ w0w, const float* __restrict__ w0b,
           const float* __restrict__ w1w, const float* __restrict__ w1b,
           const float* __restrict__ gwi, const float* __restrict__ gbi,
           float* __restrict__ gi0out)
{
    extern __shared__ float sm[];
    float* A  = sm;                  // rows [s][ch][36], sample stride SROW
    float* Bb = sm + SPB * SROW;     // rows OR xft/oft float2 [p][ch][s]
    float* mv = Bb + SPB * SROW;     // [ch*8 + s]
    float* rv = mv + 528;

    const float2* F2  = (const float2*)(ws + F2_OFF);
    const float2* G2  = (const float2*)(ws + G2_OFF);
    const float2* FS2 = (const float2*)(ws + FS_OFF);

    const int tid = threadIdx.x;
    const int n0 = blockIdx.x * SPB;
    const int s = tid & 7, ch = tid >> 3;
    const bool actC = tid < 528;

    // ---- P0 embed: h = [x,gx,gy]@p_w + p_b, stats in-reg, write row + stats ----
    if (actC) {
        float pw0 = p_w[ch], pw1 = p_w[66 + ch], pw2 = p_w[132 + ch], pb = p_b[ch];
        const float4* xr = (const float4*)(X + (size_t)(n0 + s) * 36);
        float h[36];
        float sum = 0.f, sq = 0.f;
        #pragma unroll
        for (int q = 0; q < 9; ++q) {
            float4 v = xr[q];
            float vv[4] = {v.x, v.y, v.z, v.w};
            #pragma unroll
            for (int e = 0; e < 4; ++e) {
                int pix = 4 * q + e;
                int px = pix / 6, py = pix % 6;
                float t = fmaf(vv[e] + 0.01f, pw0,
                          fmaf(px * 0.2f, pw1, fmaf(py * 0.2f, pw2, pb)));
                h[pix] = t; sum += t; sq = fmaf(t, t, sq);
            }
        }
        float m = sum * (1.f / 36.f);
        mv[ch * 8 + s] = m;
        rv[ch * 8 + s] = rsqrtf(sq * (1.f / 36.f) - m * m + 1e-5f);
        store_row36(A + s * SROW + ch * 36, h);
    }
    __syncthreads();

    for (int L = 0; L < 2; ++L) {
        const float* maw = L ? m1aw : m0aw;
        const float* mab = L ? m1ab : m0ab;
        const float* mbw = L ? m1bw : m0bw;
        const float* mbb = L ? m1bb : m0bb;
        const float* skw = L ? w1w : w0w;
        const float* skb = L ? w1b : w0b;
        const float2* packL = ((const float2*)ws) + (size_t)L * NPOS * W66 * W66;

        // ---- F: forward DFT (norm folded): A row -> xft [p][ch][s] float2 ----
        if (actC) {
            float h[36];
            load_row36(h, A + s * SROW + ch * 36);
            float m = mv[ch * 8 + s], rs = rv[ch * 8 + s];
            float2* xf = (float2*)Bb;
            #pragma unroll 1
            for (int p = 0; p < 18; ++p) {
                const float2* fr = F2 + p * 36;
                float sr = 0.f, si = 0.f, sr1 = 0.f, si1 = 0.f;
                #pragma unroll
                for (int k = 0; k < 36; k += 2) {
                    float2 f0 = fr[k], f1 = fr[k + 1];
                    sr  = fmaf(h[k],     f0.x, sr);   si  = fmaf(h[k],     f0.y, si);
                    sr1 = fmaf(h[k + 1], f1.x, sr1);  si1 = fmaf(h[k + 1], f1.y, si1);
                }
                float2 fs = FS2[p];
                xf[((size_t)p * 66 + ch) * 8 + s] =
                    make_float2(rs * ((sr + sr1) - m * fs.x), rs * ((si + si1) - m * fs.y));
            }
        }
        __syncthreads();  // xft ready

        // ---- M: channel mix, units (p, o-pair) = 594 ----
        {
            float ar0[8], ai0[8], ar1[8], ai1[8];
            const bool actM = tid < 594;
            int p = 0, o0 = 0;
            if (actM) { p = tid / 33; o0 = (tid - p * 33) * 2; }
            if (actM) {
                #pragma unroll
                for (int q = 0; q < 8; ++q) { ar0[q]=0.f; ai0[q]=0.f; ar1[q]=0.f; ai1[q]=0.f; }
                const float2* xf = (const float2*)Bb + (size_t)p * 528;   // [i][s]
                const float2* wp = packL + (size_t)p * 66 * 66;           // [i][o]
                #pragma unroll 1
                for (int i = 0; i < 66; ++i) {
                    const float4* xv = (const float4*)(xf + i * 8);
                    float4 x0 = xv[0], x1 = xv[1], x2 = xv[2], x3 = xv[3];
                    float4 wv = *(const float4*)(wp + i * 66 + o0);   // w0r,w0i,w1r,w1i
                    float xr[8] = {x0.x, x0.z, x1.x, x1.z, x2.x, x2.z, x3.x, x3.z};
                    float xi[8] = {x0.y, x0.w, x1.y, x1.w, x2.y, x2.w, x3.y, x3.w};
                    #pragma unroll
                    for (int q = 0; q < 8; ++q) {
                        ar0[q] = fmaf(xr[q], wv.x, ar0[q]); ar0[q] = fmaf(xi[q], -wv.y, ar0[q]);
                        ai0[q] = fmaf(xr[q], wv.y, ai0[q]); ai0[q] = fmaf(xi[q],  wv.x, ai0[q]);
                        ar1[q] = fmaf(xr[q], wv.z, ar1[q]); ar1[q] = fmaf(xi[q], -wv.w, ar1[q]);
                        ai1[q] = fmaf(xr[q], wv.w, ai1[q]); ai1[q] = fmaf(xi[q],  wv.z, ai1[q]);
                    }
                }
            }
            __syncthreads();  // all xft reads done
            if (actM) {
                float2* xf = (float2*)Bb;
                float4* d0 = (float4*)(xf + ((size_t)p * 66 + o0) * 8);
                float4* d1 = (float4*)(xf + ((size_t)p * 66 + o0 + 1) * 8);
                #pragma unroll
                for (int q = 0; q < 4; ++q) {
                    d0[q] = make_float4(ar0[2*q], ai0[2*q], ar0[2*q+1], ai0[2*q+1]);
                    d1[q] = make_float4(ar1[2*q], ai1[2*q], ar1[2*q+1], ai1[2*q+1]);
                }
            }
        }
        __syncthreads();  // oft ready

        // ---- I: inverse DFT + stats, write spatial rows ----
        {
            float sp[36];
            float m2 = 0.f, rs2 = 0.f;
            if (actC) {
                #pragma unroll
                for (int pix = 0; pix < 36; ++pix) sp[pix] = 0.f;
                const float2* xf = (const float2*)Bb;
                #pragma unroll 1
                for (int p = 0; p < 18; ++p) {
                    float2 ov = xf[((size_t)p * 66 + ch) * 8 + s];
                    const float2* gp = G2 + p * 36;
                    #pragma unroll
                    for (int pix = 0; pix < 36; ++pix) {
                        float2 g = gp[pix];
                        sp[pix] = fmaf(g.x, ov.x, sp[pix]);
                        sp[pix] = fmaf(g.y, ov.y, sp[pix]);
                    }
                }
                float sum = 0.f, sq = 0.f;
                #pragma unroll
                for (int pix = 0; pix < 36; ++pix) { sum += sp[pix]; sq = fmaf(sp[pix], sp[pix], sq); }
                float m = sum * (1.f / 36.f);
                m2 = m; rs2 = rsqrtf(sq * (1.f / 36.f) - m * m + 1e-5f);
            }
            __syncthreads();  // all oft reads done
            if (actC) {
                store_row36(Bb + s * SROW + ch * 36, sp);
                mv[ch * 8 + s] = m2; rv[ch * 8 + s] = rs2;
            }
        }
        __syncthreads();  // spatial + stats ready

        // ---- C1: conv1 (norm folded) + gelu, units (s, o-triple) = 176 ----
        {
            float a0[36], a1[36], a2[36];
            const bool actK = tid < 176;
            int s2 = 0, o0 = 0;
            if (actK) { s2 = tid & 7; o0 = (tid >> 3) * 3; }
            if (actK) {
                #pragma unroll
                for (int x = 0; x < 36; ++x) { a0[x] = 0.f; a1[x] = 0.f; a2[x] = 0.f; }
                float c0 = 0.f, c1 = 0.f, c2 = 0.f;
                #pragma unroll 1
                for (int i = 0; i < 66; ++i) {
                    float rs = rv[i * 8 + s2], mm = mv[i * 8 + s2];
                    float w0 = maw[(o0 + 0) * 66 + i] * rs;
                    float w1 = maw[(o0 + 1) * 66 + i] * rs;
                    float w2 = maw[(o0 + 2) * 66 + i] * rs;
                    c0 = fmaf(w0, mm, c0); c1 = fmaf(w1, mm, c1); c2 = fmaf(w2, mm, c2);
                    const float4* xr = (const float4*)(Bb + s2 * SROW + i * 36);
                    #pragma unroll
                    for (int q = 0; q < 9; ++q) {
                        float4 v = xr[q];
                        float vv[4] = {v.x, v.y, v.z, v.w};
                        #pragma unroll
                        for (int e = 0; e < 4; ++e) {
                            a0[4*q+e] = fmaf(w0, vv[e], a0[4*q+e]);
                            a1[4*q+e] = fmaf(w1, vv[e], a1[4*q+e]);
                            a2[4*q+e] = fmaf(w2, vv[e], a2[4*q+e]);
                        }
                    }
                }
                float b0 = mab[o0] - c0, b1 = mab[o0 + 1] - c1, b2 = mab[o0 + 2] - c2;
                #pragma unroll
                for (int x = 0; x < 36; ++x) {
                    a0[x] = gelu_f(a0[x] + b0);
                    a1[x] = gelu_f(a1[x] + b1);
                    a2[x] = gelu_f(a2[x] + b2);
                }
            }
            __syncthreads();  // all spatial reads done
            if (actK) {
                store_row36(Bb + s2 * SROW + (o0 + 0) * 36, a0);
                store_row36(Bb + s2 * SROW + (o0 + 1) * 36, a1);
                store_row36(Bb + s2 * SROW + (o0 + 2) * 36, a2);
            }
        }
        __syncthreads();  // t ready

        // ---- C2: conv2 + skip conv (fused acc) + gelu + stats -> A ----
        {
            float a0[36], a1[36], a2[36];
            float st[6];
            const bool actK = tid < 176;
            int s2 = 0, o0 = 0;
            if (actK) { s2 = tid & 7; o0 = (tid >> 3) * 3; }
            if (actK) {
                float i0 = mbb[o0] + skb[o0], i1 = mbb[o0+1] + skb[o0+1], i2 = mbb[o0+2] + skb[o0+2];
                #pragma unroll
                for (int x = 0; x < 36; ++x) { a0[x] = i0; a1[x] = i1; a2[x] = i2; }
                #pragma unroll 1
                for (int i = 0; i < 66; ++i) {
                    float y0 = mbw[(o0 + 0) * 66 + i];
                    float y1 = mbw[(o0 + 1) * 66 + i];
                    float y2 = mbw[(o0 + 2) * 66 + i];
                    float k0 = skw[(o0 + 0) * 66 + i];
                    float k1 = skw[(o0 + 1) * 66 + i];
                    float k2 = skw[(o0 + 2) * 66 + i];
                    const float4* tr = (const float4*)(Bb + s2 * SROW + i * 36);
                    const float4* arr = (const float4*)(A + s2 * SROW + i * 36);
                    #pragma unroll
                    for (int q = 0; q < 9; ++q) {
                        float4 tv = tr[q], av = arr[q];
                        float tvv[4] = {tv.x, tv.y, tv.z, tv.w};
                        float avv[4] = {av.x, av.y, av.z, av.w};
                        #pragma unroll
                        for (int e = 0; e < 4; ++e) {
                            a0[4*q+e] = fmaf(y0, tvv[e], fmaf(k0, avv[e], a0[4*q+e]));
                            a1[4*q+e] = fmaf(y1, tvv[e], fmaf(k1, avv[e], a1[4*q+e]));
                            a2[4*q+e] = fmaf(y2, tvv[e], fmaf(k2, avv[e], a2[4*q+e]));
                        }
                    }
                }
                float s0 = 0.f, q0 = 0.f, s1 = 0.f, q1 = 0.f, s2s = 0.f, q2 = 0.f;
                #pragma unroll
                for (int x = 0; x < 36; ++x) {
                    a0[x] = gelu_f(a0[x]); s0 += a0[x]; q0 = fmaf(a0[x], a0[x], q0);
                    a1[x] = gelu_f(a1[x]); s1 += a1[x]; q1 = fmaf(a1[x], a1[x], q1);
                    a2[x] = gelu_f(a2[x]); s2s += a2[x]; q2 = fmaf(a2[x], a2[x], q2);
                }
                st[0] = s0 * (1.f/36.f); st[1] = rsqrtf(q0*(1.f/36.f) - st[0]*st[0] + 1e-5f);
                st[2] = s1 * (1.f/36.f); st[3] = rsqrtf(q1*(1.f/36.f) - st[2]*st[2] + 1e-5f);
                st[4] = s2s * (1.f/36.f); st[5] = rsqrtf(q2*(1.f/36.f) - st[4]*st[4] + 1e-5f);
            }
            __syncthreads();  // all t/A reads done
            if (actK) {
                store_row36(A + s2 * SROW + (o0 + 0) * 36, a0);
                store_row36(A + s2 * SROW + (o0 + 1) * 36, a1);
                store_row36(A + s2 * SROW + (o0 + 2) * 36, a2);
                mv[(o0 + 0) * 8 + s2] = st[0]; rv[(o0 + 0) * 8 + s2] = st[1];
                mv[(o0 + 1) * 8 + s2] = st[2]; rv[(o0 + 1) * 8 + s2] = st[3];
                mv[(o0 + 2) * 8 + s2] = st[4]; rv[(o0 + 2) * 8 + s2] = st[5];
            }
        }
        __syncthreads();  // new A + stats ready
    }

    // ---- epilogue: gi0 = feats @ Wi0^T + bi0; units (third, s, g) = 1152 ----
    #pragma unroll
    for (int rnd = 0; rnd < 2; ++rnd) {
        int u = tid + rnd * NTH;
        if (u < 1152) {
            int third = u / 384, sg = u - third * 384;
            int es = sg & 7, g = sg >> 3;
            const float* ab = A + es * SROW + third * 22 * 36;
            const float* wb = gwi + (size_t)g * FEAT + third * 792;
            float a0 = 0.f, a1 = 0.f, a2 = 0.f, a3 = 0.f;
            #pragma unroll 1
            for (int w = 0; w < 22; ++w) {
                const float4* ar4 = (const float4*)(ab + w * 36);
                const float4* wr4 = (const float4*)(wb + w * 36);
                #pragma unroll
                for (int q = 0; q < 9; ++q) {
                    float4 av = ar4[q], wv = wr4[q];
                    a0 = fmaf(av.x, wv.x, a0); a1 = fmaf(av.y, wv.y, a1);
                    a2 = fmaf(av.z, wv.z, a2); a3 = fmaf(av.w, wv.w, a3);
                }
            }
            Bb[u] = (a0 + a1) + (a2 + a3);
        }
    }
    __syncthreads();
    if (tid < 384) {
        int es = tid & 7, g = tid >> 3;
        gi0out[(size_t)(n0 + es) * 48 + g] = Bb[tid] + Bb[tid + 384] + Bb[tid + 768] + gbi[g];
    }
}

// fused GRU0 + GRU1 + output linear; one block per batch element, one wave.
extern "C" __global__ void __launch_bounds__(64, 1)
gru_kernel(const float* __restrict__ gi0, const float* __restrict__ wh0,
           const float* __restrict__ bh0, const float* __restrict__ wi1,
           const float* __restrict__ wh1, const float* __restrict__ bi1,
           const float* __restrict__ bh1, const float* __restrict__ outw,
           const float* __restrict__ outb, float* __restrict__ y)
{
    int b = blockIdx.x;
    int g = threadIdx.x;
    int gw = (g < 48) ? g : 0;
    float rwh0[16], rwi1[16], rwh1[16];
    #pragma unroll
    for (int j = 0; j < 16; ++j) {
        rwh0[j] = wh0[gw * 16 + j];
        rwi1[j] = wi1[gw * 16 + j];
        rwh1[j] = wh1[gw * 16 + j];
    }
    float vbh0 = bh0[gw], vbi1 = bi1[gw], vbh1 = bh1[gw];
    float vow = (g < 16) ? outw[g] : 0.f;
    float ob = outb[0];
    float h0 = 0.f, h1 = 0.f;
    int base = b * TT;
    int j = g & 15;
    float cur = (g < 48) ? gi0[(size_t)base * 48 + g] : 0.f;
    for (int t = 0; t < TT; ++t) {
        int tn = (t + 1 < TT) ? t + 1 : t;
        float nxt = (g < 48) ? gi0[((size_t)base + tn) * 48 + g] : 0.f;
        float gh0 = vbh0;
        #pragma unroll
        for (int k = 0; k < 16; ++k) gh0 = fmaf(rwh0[k], __shfl(h0, k), gh0);
        float gir = __shfl(cur, j), giz = __shfl(cur, 16 + j), gin = __shfl(cur, 32 + j);
        float ghr = __shfl(gh0, j), ghz = __shfl(gh0, 16 + j), ghn = __shfl(gh0, 32 + j);
        float r = 1.f / (1.f + expf(-(gir + ghr)));
        float z = 1.f / (1.f + expf(-(giz + ghz)));
        float n = tanhf(gin + r * ghn);
        h0 = (1.f - z) * n + z * h0;
        float gi1 = vbi1, gh1 = vbh1;
        #pragma unroll
        for (int k = 0; k < 16; ++k) {
            gi1 = fmaf(rwi1[k], __shfl(h0, k), gi1);
            gh1 = fmaf(rwh1[k], __shfl(h1, k), gh1);
        }
        float air = __shfl(gi1, j) + __shfl(gh1, j);
        float aiz = __shfl(gi1, 16 + j) + __shfl(gh1, 16 + j);
        float r1 = 1.f / (1.f + expf(-air));
        float z1 = 1.f / (1.f + expf(-aiz));
        float n1 = tanhf(__shfl(gi1, 32 + j) + r1 * __shfl(gh1, 32 + j));
        h1 = (1.f - z1) * n1 + z1 * h1;
        float v = h1 * vow;
        #pragma unroll
        for (int off = 32; off; off >>= 1) v += __shfl_xor(v, off);
        if (g == 0) y[base + t] = v + ob;
        cur = nxt;
    }
}

extern "C" void kernel_launch(void* const* d_in, const int* in_sizes, int n_in,
                              void* d_out, int out_size, void* d_ws, size_t ws_size,
                              hipStream_t stream) {
    const float* X    = (const float*)d_in[0];
    const float* p_w  = (const float*)d_in[1];
    const float* p_b  = (const float*)d_in[2];
    const float* c0w1r = (const float*)d_in[3];
    const float* c0w1i = (const float*)d_in[4];
    const float* c0w2r = (const float*)d_in[5];
    const float* c0w2i = (const float*)d_in[6];
    const float* c1w1r = (const float*)d_in[7];
    const float* c1w1i = (const float*)d_in[8];
    const float* c1w2r = (const float*)d_in[9];
    const float* c1w2i = (const float*)d_in[10];
    const float* m0aw = (const float*)d_in[11];
    const float* m0ab = (const float*)d_in[12];
    const float* m0bw = (const float*)d_in[13];
    const float* m0bb = (const float*)d_in[14];
    const float* m1aw = (const float*)d_in[15];
    const float* m1ab = (const float*)d_in[16];
    const float* m1bw = (const float*)d_in[17];
    const float* m1bb = (const float*)d_in[18];
    const float* w0w  = (const float*)d_in[19];
    const float* w0b  = (const float*)d_in[20];
    const float* w1w  = (const float*)d_in[21];
    const float* w1b  = (const float*)d_in[22];
    const float* g0wi = (const float*)d_in[23];
    const float* g0wh = (const float*)d_in[24];
    const float* g0bi = (const float*)d_in[25];
    const float* g0bh = (const float*)d_in[26];
    const float* g1wi = (const float*)d_in[27];
    const float* g1wh = (const float*)d_in[28];
    const float* g1bi = (const float*)d_in[29];
    const float* g1bh = (const float*)d_in[30];
    const float* outw = (const float*)d_in[31];
    const float* outb = (const float*)d_in[32];
    float* out = (float*)d_out;

    float* ws   = (float*)d_ws;
    float* gi0  = ws + GI0_OFF;

    repack_kernel<<<(2 * NPOS * W66 * W66 + 255) / 256, 256, 0, stream>>>(
        c0w1r, c0w1i, c0w2r, c0w2i, c1w1r, c1w1i, c1w2r, c1w2i, ws);

    size_t lds = (size_t)(2 * SPB * SROW + 2 * 528) * sizeof(float);  // 156544 B
    hipFuncSetAttribute(reinterpret_cast<const void*>(fno_kernel),
                        hipFuncAttributeMaxDynamicSharedMemorySize, (int)lds);
    fno_kernel<<<NSAMP / SPB, NTH, lds, stream>>>(
        X, p_w, p_b, ws,
        m0aw, m0ab, m0bw, m0bb,
        m1aw, m1ab, m1bw, m1bb,
        w0w, w0b, w1w, w1b,
        g0wi, g0bi, gi0);

    gru_kernel<<<64, 64, 0, stream>>>(gi0, g0wh, g0bh, g1wi, g1wh, g1bi, g1bh, outw, outb, out);
}

// Round 5
// 2762.097 us; speedup vs baseline: 1.6735x; 1.6735x over previous
//
#include <hip/hip_runtime.h>

#define NTH 640          // 10 waves, 1 block/CU (LDS-limited)
#define SPB 8            // samples per block
#define W66 66
#define PIX36 36
#define NPOS 18          // kx in 0..5, ky in 0..2
#define FEAT 2376        // 66*36
#define TT 256
#define NSAMP 16384
#define SROW 2380        // padded floats per sample row buffer (36*66 + 4); 2380%32=12

// ws float offsets
#define PACK_FLOATS (2 * NPOS * W66 * W66)    // 313632
#define F2_OFF   PACK_FLOATS                  // 648 float2
#define G2_OFF   (F2_OFF + 1296)              // 648 float2
#define FS_OFF   (G2_OFF + 1296)              // 18 float2 (pad to 72)
#define GI0_OFF  (FS_OFF + 72)

__constant__ float COS6[6] = {1.f, 0.5f, -0.5f, -1.f, -0.5f, 0.5f};
__constant__ float SIN6[6] = {0.f, 0.8660254037844386468f, 0.8660254037844386468f,
                              0.f, -0.8660254037844386468f, -0.8660254037844386468f};

__device__ __forceinline__ float gelu_f(float v) {
    return 0.5f * v * (1.f + erff(v * 0.70710678118654752440f));
}

__device__ __forceinline__ void store_row36(float* p, const float* d) {
    float4* r = (float4*)p;
    #pragma unroll
    for (int q = 0; q < 9; ++q)
        r[q] = make_float4(d[4*q], d[4*q+1], d[4*q+2], d[4*q+3]);
}

// repack spectral weights into pack[L][p][i][o][{re,im}], p = kx*3+ky, kx 0..5
// and build DFT tables F2[p][k], G2[p][pix], Fsum2[p] in global ws.
extern "C" __global__ void repack_kernel(
    const float* __restrict__ w1r0, const float* __restrict__ w1i0,
    const float* __restrict__ w2r0, const float* __restrict__ w2i0,
    const float* __restrict__ w1r1, const float* __restrict__ w1i1,
    const float* __restrict__ w2r1, const float* __restrict__ w2i1,
    float* __restrict__ ws)
{
    int e = blockIdx.x * blockDim.x + threadIdx.x;
    const int TOT = 2 * NPOS * W66 * W66;
    if (e < TOT) {
        int L = e / (NPOS * W66 * W66);
        int r = e % (NPOS * W66 * W66);
        int p = r / (W66 * W66);
        int io = r % (W66 * W66);
        int i = io / W66, o = io % W66;
        int kx = p / 3, ky = p % 3;
        const float *wr, *wi;
        int kxw;
        if (L == 0) { if (kx < 3) { wr = w1r0; wi = w1i0; kxw = kx; } else { wr = w2r0; wi = w2i0; kxw = kx - 3; } }
        else        { if (kx < 3) { wr = w1r1; wi = w1i1; kxw = kx; } else { wr = w2r1; wi = w2i1; kxw = kx - 3; } }
        int src = ((i * W66 + o) * 3 + kxw) * 3 + ky;
        ws[(size_t)e * 2 + 0] = wr[src];
        ws[(size_t)e * 2 + 1] = wi[src];
    }
    if (e < NPOS * PIX36) {       // F2 and G2 tables
        int p = e / PIX36, k = e % PIX36;
        int kx = p / 3, ky = p % 3;
        int px = k / 6, py = k % 6;
        int m6 = (kx * px + ky * py) % 6;
        ws[F2_OFF + 2 * e + 0] = COS6[m6];
        ws[F2_OFF + 2 * e + 1] = -SIN6[m6];
        float ck = (ky == 0) ? (1.f / 36.f) : (1.f / 18.f);
        ws[G2_OFF + 2 * e + 0] = ck * COS6[m6];
        ws[G2_OFF + 2 * e + 1] = -ck * SIN6[m6];
    }
    if (e < NPOS) {               // Fsum2[p]
        int kx = e / 3, ky = e % 3;
        float sr = 0.f, si = 0.f;
        for (int k = 0; k < PIX36; ++k) {
            int m6 = (kx * (k / 6) + ky * (k % 6)) % 6;
            sr += COS6[m6]; si -= SIN6[m6];
        }
        ws[FS_OFF + 2 * e + 0] = sr;
        ws[FS_OFF + 2 * e + 1] = si;
    }
}

extern "C" __global__ void __launch_bounds__(NTH)
fno_kernel(const float* __restrict__ X, const float* __restrict__ p_w,
           const float* __restrict__ p_b, const float* __restrict__ ws,
           const float* __restrict__ m0aw, const float* __restrict__ m0ab,
           const float* __restrict__ m0bw, const float* __restrict__ m0bb,
           const float* __restrict__ m1aw, const float* __restrict__ m1ab,
           const float* __restrict__ m1bw, const float* __restrict__ m1bb,
           const float* __restrict__ w0w, const float* __restrict__ w0b,
           const float* __restrict__ w1w, const float* __restrict__ w1b,
           const float* __restrict__ gwi, const float* __restrict__ gbi,
           float* __restrict__ gi0out)
{
    extern __shared__ float sm[];
    float* A  = sm;                  // rows [s][ch][36], sample stride SROW (skip input)
    float* Bb = sm + SPB * SROW;     // xft/oft float2 [p][ch][s]  OR  rows [s][ch][36]
    float* mv = Bb + SPB * SROW;     // I-phase stats [ch*8 + s]
    float* rv = mv + 528;

    const float2* F2  = (const float2*)(ws + F2_OFF);
    const float2* G2  = (const float2*)(ws + G2_OFF);
    const float2* FS2 = (const float2*)(ws + FS_OFF);

    const int tid = threadIdx.x;
    const int n0 = blockIdx.x * SPB;
    const int s = tid & 7, ch = tid >> 3;    // unit mapping for embed/F/I/C1/C2
    const bool actC = tid < 528;

    // h/hm/hrs: carried ONLY from embed/C2 into the immediately-following F.
    // Dead during M/I/C1 (reassigned in C2) -> short live range, no spills.
    float h[36], hm = 0.f, hrs = 0.f;

    // ---- embed: h = [x,gx,gy]@p_w + p_b, stats in-reg, store skip row ----
    if (actC) {
        float pw0 = p_w[ch], pw1 = p_w[66 + ch], pw2 = p_w[132 + ch], pb = p_b[ch];
        const float4* xr = (const float4*)(X + (size_t)(n0 + s) * 36);
        float sum = 0.f, sq = 0.f;
        #pragma unroll
        for (int q = 0; q < 9; ++q) {
            float4 v = xr[q];
            float vv[4] = {v.x, v.y, v.z, v.w};
            #pragma unroll
            for (int e = 0; e < 4; ++e) {
                int pix = 4 * q + e;
                int px = pix / 6, py = pix % 6;
                float t = fmaf(vv[e] + 0.01f, pw0,
                          fmaf(px * 0.2f, pw1, fmaf(py * 0.2f, pw2, pb)));
                h[pix] = t; sum += t; sq = fmaf(t, t, sq);
            }
        }
        hm = sum * (1.f / 36.f);
        hrs = rsqrtf(sq * (1.f / 36.f) - hm * hm + 1e-5f);
        store_row36(A + s * SROW + ch * 36, h);
    }
    // no barrier needed: F below uses only this thread's h; Bb unread until B1.

    for (int L = 0; L < 2; ++L) {
        const float* maw = L ? m1aw : m0aw;
        const float* mab = L ? m1ab : m0ab;
        const float* mbw = L ? m1bw : m0bw;
        const float* mbb = L ? m1bb : m0bb;
        const float* skw = L ? w1w : w0w;
        const float* skb = L ? w1b : w0b;
        const float2* packL = ((const float2*)ws) + (size_t)L * NPOS * W66 * W66;

        // ---- F: forward DFT from h regs (norm folded) -> xft [p][ch][s] float2 ----
        if (actC) {
            float2* xf = (float2*)Bb;
            #pragma unroll 1
            for (int p = 0; p < 18; ++p) {
                const float2* fr = F2 + p * 36;
                float sr = 0.f, si = 0.f, sr1 = 0.f, si1 = 0.f;
                #pragma unroll
                for (int k = 0; k < 36; k += 2) {
                    float2 f0 = fr[k], f1 = fr[k + 1];
                    sr  = fmaf(h[k],     f0.x, sr);   si  = fmaf(h[k],     f0.y, si);
                    sr1 = fmaf(h[k + 1], f1.x, sr1);  si1 = fmaf(h[k + 1], f1.y, si1);
                }
                float2 fs = FS2[p];
                xf[((size_t)p * 66 + ch) * 8 + s] =
                    make_float2(hrs * ((sr + sr1) - hm * fs.x), hrs * ((si + si1) - hm * fs.y));
            }
        }
        __syncthreads();  // B1: xft ready

        // ---- M: channel mix, units (p, o-pair) = 594 ----
        {
            float ar0[8], ai0[8], ar1[8], ai1[8];
            const bool actM = tid < 594;
            int p = 0, o0 = 0;
            if (actM) { p = tid / 33; o0 = (tid - p * 33) * 2; }
            if (actM) {
                #pragma unroll
                for (int q = 0; q < 8; ++q) { ar0[q]=0.f; ai0[q]=0.f; ar1[q]=0.f; ai1[q]=0.f; }
                const float2* xf = (const float2*)Bb + (size_t)p * 528;   // [i][s]
                const float2* wp = packL + (size_t)p * 66 * 66;           // [i][o]
                #pragma unroll 1
                for (int i = 0; i < 66; ++i) {
                    const float4* xv = (const float4*)(xf + i * 8);
                    float4 x0 = xv[0], x1 = xv[1], x2 = xv[2], x3 = xv[3];
                    float4 wv = *(const float4*)(wp + i * 66 + o0);   // w0r,w0i,w1r,w1i
                    float xr[8] = {x0.x, x0.z, x1.x, x1.z, x2.x, x2.z, x3.x, x3.z};
                    float xi[8] = {x0.y, x0.w, x1.y, x1.w, x2.y, x2.w, x3.y, x3.w};
                    #pragma unroll
                    for (int q = 0; q < 8; ++q) {
                        ar0[q] = fmaf(xr[q], wv.x, ar0[q]); ar0[q] = fmaf(xi[q], -wv.y, ar0[q]);
                        ai0[q] = fmaf(xr[q], wv.y, ai0[q]); ai0[q] = fmaf(xi[q],  wv.x, ai0[q]);
                        ar1[q] = fmaf(xr[q], wv.z, ar1[q]); ar1[q] = fmaf(xi[q], -wv.w, ar1[q]);
                        ai1[q] = fmaf(xr[q], wv.w, ai1[q]); ai1[q] = fmaf(xi[q],  wv.z, ai1[q]);
                    }
                }
            }
            __syncthreads();  // B2: all xft reads done
            if (actM) {
                float2* xf = (float2*)Bb;
                float4* d0 = (float4*)(xf + ((size_t)p * 66 + o0) * 8);
                float4* d1 = (float4*)(xf + ((size_t)p * 66 + o0 + 1) * 8);
                #pragma unroll
                for (int q = 0; q < 4; ++q) {
                    d0[q] = make_float4(ar0[2*q], ai0[2*q], ar0[2*q+1], ai0[2*q+1]);
                    d1[q] = make_float4(ar1[2*q], ai1[2*q], ar1[2*q+1], ai1[2*q+1]);
                }
            }
        }
        __syncthreads();  // B3: oft ready

        // ---- I: inverse DFT + stats (one sp[36] live) -> spatial rows + LDS stats ----
        {
            float sp[36];
            float m2 = 0.f, rs2 = 0.f;
            if (actC) {
                #pragma unroll
                for (int pix = 0; pix < 36; ++pix) sp[pix] = 0.f;
                const float2* xf = (const float2*)Bb;
                #pragma unroll 1
                for (int p = 0; p < 18; ++p) {
                    float2 ov = xf[((size_t)p * 66 + ch) * 8 + s];
                    const float2* gp = G2 + p * 36;
                    #pragma unroll
                    for (int pix = 0; pix < 36; ++pix) {
                        float2 g = gp[pix];
                        sp[pix] = fmaf(g.x, ov.x, sp[pix]);
                        sp[pix] = fmaf(g.y, ov.y, sp[pix]);
                    }
                }
                float sum = 0.f, sq = 0.f;
                #pragma unroll
                for (int pix = 0; pix < 36; ++pix) { sum += sp[pix]; sq = fmaf(sp[pix], sp[pix], sq); }
                float m = sum * (1.f / 36.f);
                m2 = m; rs2 = rsqrtf(sq * (1.f / 36.f) - m * m + 1e-5f);
            }
            __syncthreads();  // B4: all oft reads done
            if (actC) {
                store_row36(Bb + s * SROW + ch * 36, sp);
                mv[ch * 8 + s] = m2; rv[ch * 8 + s] = rs2;
            }
        }
        __syncthreads();  // B5: spatial + stats ready

        // ---- C1: conv1 (norm folded) + gelu, units (s, o) = 528, one acc[36] ----
        {
            float acc[36];
            if (actC) {
                #pragma unroll
                for (int x = 0; x < 36; ++x) acc[x] = 0.f;
                float corr = 0.f;
                #pragma unroll 1
                for (int i = 0; i < 66; ++i) {
                    float w = maw[ch * 66 + i] * rv[i * 8 + s];
                    corr = fmaf(w, mv[i * 8 + s], corr);
                    const float4* xr = (const float4*)(Bb + s * SROW + i * 36);
                    #pragma unroll
                    for (int q = 0; q < 9; ++q) {
                        float4 v = xr[q];
                        acc[4*q+0] = fmaf(w, v.x, acc[4*q+0]);
                        acc[4*q+1] = fmaf(w, v.y, acc[4*q+1]);
                        acc[4*q+2] = fmaf(w, v.z, acc[4*q+2]);
                        acc[4*q+3] = fmaf(w, v.w, acc[4*q+3]);
                    }
                }
                float b = mab[ch] - corr;
                #pragma unroll
                for (int x = 0; x < 36; ++x) acc[x] = gelu_f(acc[x] + b);
            }
            __syncthreads();  // B6: all spatial reads done
            if (actC) store_row36(Bb + s * SROW + ch * 36, acc);
        }
        __syncthreads();  // B7: t ready

        // ---- C2: conv2 + skip (fused) + gelu + stats -> h regs; store A after B8 ----
        if (actC) {
            float b0 = mbb[ch] + skb[ch];
            #pragma unroll
            for (int x = 0; x < 36; ++x) h[x] = b0;
            #pragma unroll 1
            for (int i = 0; i < 66; ++i) {
                float y = mbw[ch * 66 + i];
                float k = skw[ch * 66 + i];
                const float4* tr = (const float4*)(Bb + s * SROW + i * 36);
                const float4* ar = (const float4*)(A + s * SROW + i * 36);
                #pragma unroll
                for (int q = 0; q < 9; ++q) {
                    float4 tv = tr[q], av = ar[q];
                    h[4*q+0] = fmaf(y, tv.x, fmaf(k, av.x, h[4*q+0]));
                    h[4*q+1] = fmaf(y, tv.y, fmaf(k, av.y, h[4*q+1]));
                    h[4*q+2] = fmaf(y, tv.z, fmaf(k, av.z, h[4*q+2]));
                    h[4*q+3] = fmaf(y, tv.w, fmaf(k, av.w, h[4*q+3]));
                }
            }
            float sum = 0.f, sq = 0.f;
            #pragma unroll
            for (int x = 0; x < 36; ++x) {
                float v = gelu_f(h[x]);
                h[x] = v; sum += v; sq = fmaf(v, v, sq);
            }
            hm = sum * (1.f / 36.f);
            hrs = rsqrtf(sq * (1.f / 36.f) - hm * hm + 1e-5f);
        }
        __syncthreads();  // B8: all t/A reads done
        if (actC) store_row36(A + s * SROW + ch * 36, h);
        // next F consumes h directly from regs; its Bb writes are safe (B8 done).
    }

    __syncthreads();  // final A visible
    // ---- epilogue: gi0 = feats @ Wi0^T + bi0; units (third, s, g) = 1152 ----
    #pragma unroll
    for (int rnd = 0; rnd < 2; ++rnd) {
        int u = tid + rnd * NTH;
        if (u < 1152) {
            int third = u / 384, sg = u - third * 384;
            int es = sg & 7, g = sg >> 3;
            const float* ab = A + es * SROW + third * 22 * 36;
            const float* wb = gwi + (size_t)g * FEAT + third * 792;
            float a0 = 0.f, a1 = 0.f, a2 = 0.f, a3 = 0.f;
            #pragma unroll 1
            for (int w = 0; w < 22; ++w) {
                const float4* ar4 = (const float4*)(ab + w * 36);
                const float4* wr4 = (const float4*)(wb + w * 36);
                #pragma unroll
                for (int q = 0; q < 9; ++q) {
                    float4 av = ar4[q], wv = wr4[q];
                    a0 = fmaf(av.x, wv.x, a0); a1 = fmaf(av.y, wv.y, a1);
                    a2 = fmaf(av.z, wv.z, a2); a3 = fmaf(av.w, wv.w, a3);
                }
            }
            Bb[u] = (a0 + a1) + (a2 + a3);
        }
    }
    __syncthreads();
    if (tid < 384) {
        int es = tid & 7, g = tid >> 3;
        gi0out[(size_t)(n0 + es) * 48 + g] = Bb[tid] + Bb[tid + 384] + Bb[tid + 768] + gbi[g];
    }
}

// fused GRU0 + GRU1 + output linear; one block per batch element, one wave.
extern "C" __global__ void __launch_bounds__(64, 1)
gru_kernel(const float* __restrict__ gi0, const float* __restrict__ wh0,
           const float* __restrict__ bh0, const float* __restrict__ wi1,
           const float* __restrict__ wh1, const float* __restrict__ bi1,
           const float* __restrict__ bh1, const float* __restrict__ outw,
           const float* __restrict__ outb, float* __restrict__ y)
{
    int b = blockIdx.x;
    int g = threadIdx.x;
    int gw = (g < 48) ? g : 0;
    float rwh0[16], rwi1[16], rwh1[16];
    #pragma unroll
    for (int j = 0; j < 16; ++j) {
        rwh0[j] = wh0[gw * 16 + j];
        rwi1[j] = wi1[gw * 16 + j];
        rwh1[j] = wh1[gw * 16 + j];
    }
    float vbh0 = bh0[gw], vbi1 = bi1[gw], vbh1 = bh1[gw];
    float vow = (g < 16) ? outw[g] : 0.f;
    float ob = outb[0];
    float h0 = 0.f, h1 = 0.f;
    int base = b * TT;
    int j = g & 15;
    float cur = (g < 48) ? gi0[(size_t)base * 48 + g] : 0.f;
    for (int t = 0; t < TT; ++t) {
        int tn = (t + 1 < TT) ? t + 1 : t;
        float nxt = (g < 48) ? gi0[((size_t)base + tn) * 48 + g] : 0.f;
        float gh0 = vbh0;
        #pragma unroll
        for (int k = 0; k < 16; ++k) gh0 = fmaf(rwh0[k], __shfl(h0, k), gh0);
        float gir = __shfl(cur, j), giz = __shfl(cur, 16 + j), gin = __shfl(cur, 32 + j);
        float ghr = __shfl(gh0, j), ghz = __shfl(gh0, 16 + j), ghn = __shfl(gh0, 32 + j);
        float r = 1.f / (1.f + expf(-(gir + ghr)));
        float z = 1.f / (1.f + expf(-(giz + ghz)));
        float n = tanhf(gin + r * ghn);
        h0 = (1.f - z) * n + z * h0;
        float gi1 = vbi1, gh1 = vbh1;
        #pragma unroll
        for (int k = 0; k < 16; ++k) {
            gi1 = fmaf(rwi1[k], __shfl(h0, k), gi1);
            gh1 = fmaf(rwh1[k], __shfl(h1, k), gh1);
        }
        float air = __shfl(gi1, j) + __shfl(gh1, j);
        float aiz = __shfl(gi1, 16 + j) + __shfl(gh1, 16 + j);
        float r1 = 1.f / (1.f + expf(-air));
        float z1 = 1.f / (1.f + expf(-aiz));
        float n1 = tanhf(__shfl(gi1, 32 + j) + r1 * __shfl(gh1, 32 + j));
        h1 = (1.f - z1) * n1 + z1 * h1;
        float v = h1 * vow;
        #pragma unroll
        for (int off = 32; off; off >>= 1) v += __shfl_xor(v, off);
        if (g == 0) y[base + t] = v + ob;
        cur = nxt;
    }
}

extern "C" void kernel_launch(void* const* d_in, const int* in_sizes, int n_in,
                              void* d_out, int out_size, void* d_ws, size_t ws_size,
                              hipStream_t stream) {
    const float* X    = (const float*)d_in[0];
    const float* p_w  = (const float*)d_in[1];
    const float* p_b  = (const float*)d_in[2];
    const float* c0w1r = (const float*)d_in[3];
    const float* c0w1i = (const float*)d_in[4];
    const float* c0w2r = (const float*)d_in[5];
    const float* c0w2i = (const float*)d_in[6];
    const float* c1w1r = (const float*)d_in[7];
    const float* c1w1i = (const float*)d_in[8];
    const float* c1w2r = (const float*)d_in[9];
    const float* c1w2i = (const float*)d_in[10];
    const float* m0aw = (const float*)d_in[11];
    const float* m0ab = (const float*)d_in[12];
    const float* m0bw = (const float*)d_in[13];
    const float* m0bb = (const float*)d_in[14];
    const float* m1aw = (const float*)d_in[15];
    const float* m1ab = (const float*)d_in[16];
    const float* m1bw = (const float*)d_in[17];
    const float* m1bb = (const float*)d_in[18];
    const float* w0w  = (const float*)d_in[19];
    const float* w0b  = (const float*)d_in[20];
    const float* w1w  = (const float*)d_in[21];
    const float* w1b  = (const float*)d_in[22];
    const float* g0wi = (const float*)d_in[23];
    const float* g0wh = (const float*)d_in[24];
    const float* g0bi = (const float*)d_in[25];
    const float* g0bh = (const float*)d_in[26];
    const float* g1wi = (const float*)d_in[27];
    const float* g1wh = (const float*)d_in[28];
    const float* g1bi = (const float*)d_in[29];
    const float* g1bh = (const float*)d_in[30];
    const float* outw = (const float*)d_in[31];
    const float* outb = (const float*)d_in[32];
    float* out = (float*)d_out;

    float* ws   = (float*)d_ws;
    float* gi0  = ws + GI0_OFF;

    repack_kernel<<<(2 * NPOS * W66 * W66 + 255) / 256, 256, 0, stream>>>(
        c0w1r, c0w1i, c0w2r, c0w2i, c1w1r, c1w1i, c1w2r, c1w2i, ws);

    size_t lds = (size_t)(2 * SPB * SROW + 2 * 528) * sizeof(float);  // 156544 B
    hipFuncSetAttribute(reinterpret_cast<const void*>(fno_kernel),
                        hipFuncAttributeMaxDynamicSharedMemorySize, (int)lds);
    fno_kernel<<<NSAMP / SPB, NTH, lds, stream>>>(
        X, p_w, p_b, ws,
        m0aw, m0ab, m0bw, m0bb,
        m1aw, m1ab, m1bw, m1bb,
        w0w, w0b, w1w, w1b,
        g0wi, g0bi, gi0);

    gru_kernel<<<64, 64, 0, stream>>>(gi0, g0wh, g0bh, g1wi, g1wh, g1bi, g1bh, outw, outb, out);
}

// Round 6
// 2713.196 us; speedup vs baseline: 1.7036x; 1.0180x over previous
//
#include <hip/hip_runtime.h>

#define NTH 640          // 10 waves, 1 block/CU (LDS-limited)
#define SPB 8            // samples per block
#define W66 66
#define PIX36 36
#define NPOS 18          // kx in 0..5, ky in 0..2
#define FEAT 2376        // 66*36
#define TT 256
#define NSAMP 16384
#define SROW 2380        // padded floats per sample row buffer (36*66 + 4); 2380%32=12

// ws float offsets
#define PACK_FLOATS (2 * NPOS * W66 * W66)    // 313632
#define F2_OFF   PACK_FLOATS                  // 648 float2
#define G2_OFF   (F2_OFF + 1296)              // 648 float2
#define FS_OFF   (G2_OFF + 1296)              // 18 float2 (pad to 72)
#define GI0_OFF  (FS_OFF + 72)

__constant__ float COS6[6] = {1.f, 0.5f, -0.5f, -1.f, -0.5f, 0.5f};
__constant__ float SIN6[6] = {0.f, 0.8660254037844386468f, 0.8660254037844386468f,
                              0.f, -0.8660254037844386468f, -0.8660254037844386468f};

__device__ __forceinline__ float gelu_f(float v) {
    return 0.5f * v * (1.f + erff(v * 0.70710678118654752440f));
}

__device__ __forceinline__ void load_row36(float* d, const float* p) {
    const float4* r = (const float4*)p;
    #pragma unroll
    for (int q = 0; q < 9; ++q) {
        float4 v = r[q];
        d[4*q] = v.x; d[4*q+1] = v.y; d[4*q+2] = v.z; d[4*q+3] = v.w;
    }
}
__device__ __forceinline__ void store_row36(float* p, const float* d) {
    float4* r = (float4*)p;
    #pragma unroll
    for (int q = 0; q < 9; ++q)
        r[q] = make_float4(d[4*q], d[4*q+1], d[4*q+2], d[4*q+3]);
}

// repack spectral weights into pack[L][p][i][o][{re,im}], p = kx*3+ky, kx 0..5
// and build DFT tables F2[p][k], G2[p][pix], Fsum2[p] in global ws.
extern "C" __global__ void repack_kernel(
    const float* __restrict__ w1r0, const float* __restrict__ w1i0,
    const float* __restrict__ w2r0, const float* __restrict__ w2i0,
    const float* __restrict__ w1r1, const float* __restrict__ w1i1,
    const float* __restrict__ w2r1, const float* __restrict__ w2i1,
    float* __restrict__ ws)
{
    int e = blockIdx.x * blockDim.x + threadIdx.x;
    const int TOT = 2 * NPOS * W66 * W66;
    if (e < TOT) {
        int L = e / (NPOS * W66 * W66);
        int r = e % (NPOS * W66 * W66);
        int p = r / (W66 * W66);
        int io = r % (W66 * W66);
        int i = io / W66, o = io % W66;
        int kx = p / 3, ky = p % 3;
        const float *wr, *wi;
        int kxw;
        if (L == 0) { if (kx < 3) { wr = w1r0; wi = w1i0; kxw = kx; } else { wr = w2r0; wi = w2i0; kxw = kx - 3; } }
        else        { if (kx < 3) { wr = w1r1; wi = w1i1; kxw = kx; } else { wr = w2r1; wi = w2i1; kxw = kx - 3; } }
        int src = ((i * W66 + o) * 3 + kxw) * 3 + ky;
        ws[(size_t)e * 2 + 0] = wr[src];
        ws[(size_t)e * 2 + 1] = wi[src];
    }
    if (e < NPOS * PIX36) {       // F2 and G2 tables
        int p = e / PIX36, k = e % PIX36;
        int kx = p / 3, ky = p % 3;
        int px = k / 6, py = k % 6;
        int m6 = (kx * px + ky * py) % 6;
        ws[F2_OFF + 2 * e + 0] = COS6[m6];
        ws[F2_OFF + 2 * e + 1] = -SIN6[m6];
        float ck = (ky == 0) ? (1.f / 36.f) : (1.f / 18.f);
        ws[G2_OFF + 2 * e + 0] = ck * COS6[m6];
        ws[G2_OFF + 2 * e + 1] = -ck * SIN6[m6];
    }
    if (e < NPOS) {               // Fsum2[p]
        int kx = e / 3, ky = e % 3;
        float sr = 0.f, si = 0.f;
        for (int k = 0; k < PIX36; ++k) {
            int m6 = (kx * (k / 6) + ky * (k % 6)) % 6;
            sr += COS6[m6]; si -= SIN6[m6];
        }
        ws[FS_OFF + 2 * e + 0] = sr;
        ws[FS_OFF + 2 * e + 1] = si;
    }
}

extern "C" __global__ void
__attribute__((amdgpu_flat_work_group_size(NTH, NTH)))
__attribute__((amdgpu_waves_per_eu(3)))
fno_kernel(const float* __restrict__ X, const float* __restrict__ p_w,
           const float* __restrict__ p_b, const float* __restrict__ ws,
           const float* __restrict__ m0aw, const float* __restrict__ m0ab,
           const float* __restrict__ m0bw, const float* __restrict__ m0bb,
           const float* __restrict__ m1aw, const float* __restrict__ m1ab,
           const float* __restrict__ m1bw, const float* __restrict__ m1bb,
           const float* __restrict__ w0w, const float* __restrict__ w0b,
           const float* __restrict__ w1w, const float* __restrict__ w1b,
           const float* __restrict__ gwi, const float* __restrict__ gbi,
           float* __restrict__ gi0out)
{
    extern __shared__ float sm[];
    float* A  = sm;                  // rows [s][ch][36], sample stride SROW (skip input)
    float* Bb = sm + SPB * SROW;     // xft/oft float2 [p][ch][s]  OR  rows [s][ch][36]
    float* mv = Bb + SPB * SROW;     // stats [ch*8+s]: embed/C2 write, F reads; I writes, C1 reads
    float* rv = mv + 528;

    const float2* F2  = (const float2*)(ws + F2_OFF);
    const float2* G2  = (const float2*)(ws + G2_OFF);
    const float2* FS2 = (const float2*)(ws + FS_OFF);

    const int tid = threadIdx.x;
    const int n0 = blockIdx.x * SPB;
    const int s = tid & 7, ch = tid >> 3;    // unit mapping for embed/F/I/C1/C2
    const bool actC = tid < 528;             // note: tid == ch*8+s

    // NO register state is carried across any barrier: every phase loads its
    // input from LDS and stores its result to LDS. Max live set per phase
    // is one 36-float array + ~20 temps -> no scratch spills.

    // ---- embed: h = [x,gx,gy]@p_w + p_b, stats in-reg -> A row + mv/rv ----
    if (actC) {
        float h[36];
        float pw0 = p_w[ch], pw1 = p_w[66 + ch], pw2 = p_w[132 + ch], pb = p_b[ch];
        const float4* xr = (const float4*)(X + (size_t)(n0 + s) * 36);
        float sum = 0.f, sq = 0.f;
        #pragma unroll
        for (int q = 0; q < 9; ++q) {
            float4 v = xr[q];
            float vv[4] = {v.x, v.y, v.z, v.w};
            #pragma unroll
            for (int e = 0; e < 4; ++e) {
                int pix = 4 * q + e;
                int px = pix / 6, py = pix % 6;
                float t = fmaf(vv[e] + 0.01f, pw0,
                          fmaf(px * 0.2f, pw1, fmaf(py * 0.2f, pw2, pb)));
                h[pix] = t; sum += t; sq = fmaf(t, t, sq);
            }
        }
        float m = sum * (1.f / 36.f);
        mv[tid] = m;
        rv[tid] = rsqrtf(sq * (1.f / 36.f) - m * m + 1e-5f);
        store_row36(A + s * SROW + ch * 36, h);
    }
    // no barrier: F reads only this thread's A row and mv/rv slot.

    for (int L = 0; L < 2; ++L) {
        const float* maw = L ? m1aw : m0aw;
        const float* mab = L ? m1ab : m0ab;
        const float* mbw = L ? m1bw : m0bw;
        const float* mbb = L ? m1bb : m0bb;
        const float* skw = L ? w1w : w0w;
        const float* skb = L ? w1b : w0b;
        const float2* packL = ((const float2*)ws) + (size_t)L * NPOS * W66 * W66;

        // ---- F: forward DFT (norm folded): own A row + own stats -> xft [p][ch][s] ----
        if (actC) {
            float h[36];
            load_row36(h, A + s * SROW + ch * 36);
            float hm = mv[tid], hrs = rv[tid];
            float2* xf = (float2*)Bb;
            #pragma unroll 1
            for (int p = 0; p < 18; ++p) {
                const float2* fr = F2 + p * 36;
                float sr = 0.f, si = 0.f, sr1 = 0.f, si1 = 0.f;
                #pragma unroll
                for (int k = 0; k < 36; k += 2) {
                    float2 f0 = fr[k], f1 = fr[k + 1];
                    sr  = fmaf(h[k],     f0.x, sr);   si  = fmaf(h[k],     f0.y, si);
                    sr1 = fmaf(h[k + 1], f1.x, sr1);  si1 = fmaf(h[k + 1], f1.y, si1);
                }
                float2 fs = FS2[p];
                xf[((size_t)p * 66 + ch) * 8 + s] =
                    make_float2(hrs * ((sr + sr1) - hm * fs.x), hrs * ((si + si1) - hm * fs.y));
            }
        }
        __syncthreads();  // B1: xft ready

        // ---- M: channel mix, units (p, o-pair) = 594 ----
        {
            float ar0[8], ai0[8], ar1[8], ai1[8];
            const bool actM = tid < 594;
            int p = 0, o0 = 0;
            if (actM) { p = tid / 33; o0 = (tid - p * 33) * 2; }
            if (actM) {
                #pragma unroll
                for (int q = 0; q < 8; ++q) { ar0[q]=0.f; ai0[q]=0.f; ar1[q]=0.f; ai1[q]=0.f; }
                const float2* xf = (const float2*)Bb + (size_t)p * 528;   // [i][s]
                const float2* wp = packL + (size_t)p * 66 * 66;           // [i][o]
                #pragma unroll 1
                for (int i = 0; i < 66; ++i) {
                    const float4* xv = (const float4*)(xf + i * 8);
                    float4 x0 = xv[0], x1 = xv[1], x2 = xv[2], x3 = xv[3];
                    float4 wv = *(const float4*)(wp + i * 66 + o0);   // w0r,w0i,w1r,w1i
                    float xr[8] = {x0.x, x0.z, x1.x, x1.z, x2.x, x2.z, x3.x, x3.z};
                    float xi[8] = {x0.y, x0.w, x1.y, x1.w, x2.y, x2.w, x3.y, x3.w};
                    #pragma unroll
                    for (int q = 0; q < 8; ++q) {
                        ar0[q] = fmaf(xr[q], wv.x, ar0[q]); ar0[q] = fmaf(xi[q], -wv.y, ar0[q]);
                        ai0[q] = fmaf(xr[q], wv.y, ai0[q]); ai0[q] = fmaf(xi[q],  wv.x, ai0[q]);
                        ar1[q] = fmaf(xr[q], wv.z, ar1[q]); ar1[q] = fmaf(xi[q], -wv.w, ar1[q]);
                        ai1[q] = fmaf(xr[q], wv.w, ai1[q]); ai1[q] = fmaf(xi[q],  wv.z, ai1[q]);
                    }
                }
            }
            __syncthreads();  // B2: all xft reads done
            if (actM) {
                float2* xf = (float2*)Bb;
                float4* d0 = (float4*)(xf + ((size_t)p * 66 + o0) * 8);
                float4* d1 = (float4*)(xf + ((size_t)p * 66 + o0 + 1) * 8);
                #pragma unroll
                for (int q = 0; q < 4; ++q) {
                    d0[q] = make_float4(ar0[2*q], ai0[2*q], ar0[2*q+1], ai0[2*q+1]);
                    d1[q] = make_float4(ar1[2*q], ai1[2*q], ar1[2*q+1], ai1[2*q+1]);
                }
            }
        }
        __syncthreads();  // B3: oft ready

        // ---- I: inverse DFT + stats (one sp[36] live) -> spatial rows + mv/rv ----
        {
            float sp[36];
            float m2 = 0.f, rs2 = 0.f;
            if (actC) {
                #pragma unroll
                for (int pix = 0; pix < 36; ++pix) sp[pix] = 0.f;
                const float2* xf = (const float2*)Bb;
                #pragma unroll 1
                for (int p = 0; p < 18; ++p) {
                    float2 ov = xf[((size_t)p * 66 + ch) * 8 + s];
                    const float2* gp = G2 + p * 36;
                    #pragma unroll
                    for (int pix = 0; pix < 36; ++pix) {
                        float2 g = gp[pix];
                        sp[pix] = fmaf(g.x, ov.x, sp[pix]);
                        sp[pix] = fmaf(g.y, ov.y, sp[pix]);
                    }
                }
                float sum = 0.f, sq = 0.f;
                #pragma unroll
                for (int pix = 0; pix < 36; ++pix) { sum += sp[pix]; sq = fmaf(sp[pix], sp[pix], sq); }
                float m = sum * (1.f / 36.f);
                m2 = m; rs2 = rsqrtf(sq * (1.f / 36.f) - m * m + 1e-5f);
            }
            __syncthreads();  // B4: all oft reads done
            if (actC) {
                store_row36(Bb + s * SROW + ch * 36, sp);
                mv[tid] = m2; rv[tid] = rs2;
            }
        }
        __syncthreads();  // B5: spatial + stats ready

        // ---- C1: conv1 (norm folded) + gelu, units (s, o) = 528, one acc[36] ----
        {
            float acc[36];
            if (actC) {
                #pragma unroll
                for (int x = 0; x < 36; ++x) acc[x] = 0.f;
                float corr = 0.f;
                #pragma unroll 1
                for (int i = 0; i < 66; ++i) {
                    float w = maw[ch * 66 + i] * rv[i * 8 + s];
                    corr = fmaf(w, mv[i * 8 + s], corr);
                    const float4* xr = (const float4*)(Bb + s * SROW + i * 36);
                    #pragma unroll
                    for (int q = 0; q < 9; ++q) {
                        float4 v = xr[q];
                        acc[4*q+0] = fmaf(w, v.x, acc[4*q+0]);
                        acc[4*q+1] = fmaf(w, v.y, acc[4*q+1]);
                        acc[4*q+2] = fmaf(w, v.z, acc[4*q+2]);
                        acc[4*q+3] = fmaf(w, v.w, acc[4*q+3]);
                    }
                }
                float b = mab[ch] - corr;
                #pragma unroll
                for (int x = 0; x < 36; ++x) acc[x] = gelu_f(acc[x] + b);
            }
            __syncthreads();  // B6: all spatial reads done
            if (actC) store_row36(Bb + s * SROW + ch * 36, acc);
        }
        __syncthreads();  // B7: t ready

        // ---- C2: conv2 + skip (fused) + gelu + stats -> A row + mv/rv ----
        {
            float acc[36];
            float m2 = 0.f, rs2 = 0.f;
            if (actC) {
                float b0 = mbb[ch] + skb[ch];
                #pragma unroll
                for (int x = 0; x < 36; ++x) acc[x] = b0;
                #pragma unroll 1
                for (int i = 0; i < 66; ++i) {
                    float y = mbw[ch * 66 + i];
                    float k = skw[ch * 66 + i];
                    const float4* tr = (const float4*)(Bb + s * SROW + i * 36);
                    const float4* ar = (const float4*)(A + s * SROW + i * 36);
                    #pragma unroll
                    for (int q = 0; q < 9; ++q) {
                        float4 tv = tr[q], av = ar[q];
                        acc[4*q+0] = fmaf(y, tv.x, fmaf(k, av.x, acc[4*q+0]));
                        acc[4*q+1] = fmaf(y, tv.y, fmaf(k, av.y, acc[4*q+1]));
                        acc[4*q+2] = fmaf(y, tv.z, fmaf(k, av.z, acc[4*q+2]));
                        acc[4*q+3] = fmaf(y, tv.w, fmaf(k, av.w, acc[4*q+3]));
                    }
                }
                float sum = 0.f, sq = 0.f;
                #pragma unroll
                for (int x = 0; x < 36; ++x) {
                    float v = gelu_f(acc[x]);
                    acc[x] = v; sum += v; sq = fmaf(v, v, sq);
                }
                m2 = sum * (1.f / 36.f);
                rs2 = rsqrtf(sq * (1.f / 36.f) - m2 * m2 + 1e-5f);
            }
            __syncthreads();  // B8: all t/A reads done
            if (actC) {
                store_row36(A + s * SROW + ch * 36, acc);
                mv[tid] = m2; rv[tid] = rs2;
            }
        }
        // next F reads only own A row / own mv,rv slot (same thread wrote them);
        // F's Bb writes are safe: B8 drained all C2 reads of Bb.
    }

    __syncthreads();  // final A visible
    // ---- epilogue: gi0 = feats @ Wi0^T + bi0; units (third, s, g) = 1152 ----
    #pragma unroll
    for (int rnd = 0; rnd < 2; ++rnd) {
        int u = tid + rnd * NTH;
        if (u < 1152) {
            int third = u / 384, sg = u - third * 384;
            int es = sg & 7, g = sg >> 3;
            const float* ab = A + es * SROW + third * 22 * 36;
            const float* wb = gwi + (size_t)g * FEAT + third * 792;
            float a0 = 0.f, a1 = 0.f, a2 = 0.f, a3 = 0.f;
            #pragma unroll 1
            for (int w = 0; w < 22; ++w) {
                const float4* ar4 = (const float4*)(ab + w * 36);
                const float4* wr4 = (const float4*)(wb + w * 36);
                #pragma unroll
                for (int q = 0; q < 9; ++q) {
                    float4 av = ar4[q], wv = wr4[q];
                    a0 = fmaf(av.x, wv.x, a0); a1 = fmaf(av.y, wv.y, a1);
                    a2 = fmaf(av.z, wv.z, a2); a3 = fmaf(av.w, wv.w, a3);
                }
            }
            Bb[u] = (a0 + a1) + (a2 + a3);
        }
    }
    __syncthreads();
    if (tid < 384) {
        int es = tid & 7, g = tid >> 3;
        gi0out[(size_t)(n0 + es) * 48 + g] = Bb[tid] + Bb[tid + 384] + Bb[tid + 768] + gbi[g];
    }
}

// fused GRU0 + GRU1 + output linear; one block per batch element, one wave.
extern "C" __global__ void __launch_bounds__(64, 1)
gru_kernel(const float* __restrict__ gi0, const float* __restrict__ wh0,
           const float* __restrict__ bh0, const float* __restrict__ wi1,
           const float* __restrict__ wh1, const float* __restrict__ bi1,
           const float* __restrict__ bh1, const float* __restrict__ outw,
           const float* __restrict__ outb, float* __restrict__ y)
{
    int b = blockIdx.x;
    int g = threadIdx.x;
    int gw = (g < 48) ? g : 0;
    float rwh0[16], rwi1[16], rwh1[16];
    #pragma unroll
    for (int j = 0; j < 16; ++j) {
        rwh0[j] = wh0[gw * 16 + j];
        rwi1[j] = wi1[gw * 16 + j];
        rwh1[j] = wh1[gw * 16 + j];
    }
    float vbh0 = bh0[gw], vbi1 = bi1[gw], vbh1 = bh1[gw];
    float vow = (g < 16) ? outw[g] : 0.f;
    float ob = outb[0];
    float h0 = 0.f, h1 = 0.f;
    int base = b * TT;
    int j = g & 15;
    float cur = (g < 48) ? gi0[(size_t)base * 48 + g] : 0.f;
    for (int t = 0; t < TT; ++t) {
        int tn = (t + 1 < TT) ? t + 1 : t;
        float nxt = (g < 48) ? gi0[((size_t)base + tn) * 48 + g] : 0.f;
        float gh0 = vbh0;
        #pragma unroll
        for (int k = 0; k < 16; ++k) gh0 = fmaf(rwh0[k], __shfl(h0, k), gh0);
        float gir = __shfl(cur, j), giz = __shfl(cur, 16 + j), gin = __shfl(cur, 32 + j);
        float ghr = __shfl(gh0, j), ghz = __shfl(gh0, 16 + j), ghn = __shfl(gh0, 32 + j);
        float r = 1.f / (1.f + expf(-(gir + ghr)));
        float z = 1.f / (1.f + expf(-(giz + ghz)));
        float n = tanhf(gin + r * ghn);
        h0 = (1.f - z) * n + z * h0;
        float gi1 = vbi1, gh1 = vbh1;
        #pragma unroll
        for (int k = 0; k < 16; ++k) {
            gi1 = fmaf(rwi1[k], __shfl(h0, k), gi1);
            gh1 = fmaf(rwh1[k], __shfl(h1, k), gh1);
        }
        float air = __shfl(gi1, j) + __shfl(gh1, j);
        float aiz = __shfl(gi1, 16 + j) + __shfl(gh1, 16 + j);
        float r1 = 1.f / (1.f + expf(-air));
        float z1 = 1.f / (1.f + expf(-aiz));
        float n1 = tanhf(__shfl(gi1, 32 + j) + r1 * __shfl(gh1, 32 + j));
        h1 = (1.f - z1) * n1 + z1 * h1;
        float v = h1 * vow;
        #pragma unroll
        for (int off = 32; off; off >>= 1) v += __shfl_xor(v, off);
        if (g == 0) y[base + t] = v + ob;
        cur = nxt;
    }
}

extern "C" void kernel_launch(void* const* d_in, const int* in_sizes, int n_in,
                              void* d_out, int out_size, void* d_ws, size_t ws_size,
                              hipStream_t stream) {
    const float* X    = (const float*)d_in[0];
    const float* p_w  = (const float*)d_in[1];
    const float* p_b  = (const float*)d_in[2];
    const float* c0w1r = (const float*)d_in[3];
    const float* c0w1i = (const float*)d_in[4];
    const float* c0w2r = (const float*)d_in[5];
    const float* c0w2i = (const float*)d_in[6];
    const float* c1w1r = (const float*)d_in[7];
    const float* c1w1i = (const float*)d_in[8];
    const float* c1w2r = (const float*)d_in[9];
    const float* c1w2i = (const float*)d_in[10];
    const float* m0aw = (const float*)d_in[11];
    const float* m0ab = (const float*)d_in[12];
    const float* m0bw = (const float*)d_in[13];
    const float* m0bb = (const float*)d_in[14];
    const float* m1aw = (const float*)d_in[15];
    const float* m1ab = (const float*)d_in[16];
    const float* m1bw = (const float*)d_in[17];
    const float* m1bb = (const float*)d_in[18];
    const float* w0w  = (const float*)d_in[19];
    const float* w0b  = (const float*)d_in[20];
    const float* w1w  = (const float*)d_in[21];
    const float* w1b  = (const float*)d_in[22];
    const float* g0wi = (const float*)d_in[23];
    const float* g0wh = (const float*)d_in[24];
    const float* g0bi = (const float*)d_in[25];
    const float* g0bh = (const float*)d_in[26];
    const float* g1wi = (const float*)d_in[27];
    const float* g1wh = (const float*)d_in[28];
    const float* g1bi = (const float*)d_in[29];
    const float* g1bh = (const float*)d_in[30];
    const float* outw = (const float*)d_in[31];
    const float* outb = (const float*)d_in[32];
    float* out = (float*)d_out;

    float* ws   = (float*)d_ws;
    float* gi0  = ws + GI0_OFF;

    repack_kernel<<<(2 * NPOS * W66 * W66 + 255) / 256, 256, 0, stream>>>(
        c0w1r, c0w1i, c0w2r, c0w2i, c1w1r, c1w1i, c1w2r, c1w2i, ws);

    size_t lds = (size_t)(2 * SPB * SROW + 2 * 528) * sizeof(float);  // 156544 B
    hipFuncSetAttribute(reinterpret_cast<const void*>(fno_kernel),
                        hipFuncAttributeMaxDynamicSharedMemorySize, (int)lds);
    fno_kernel<<<NSAMP / SPB, NTH, lds, stream>>>(
        X, p_w, p_b, ws,
        m0aw, m0ab, m0bw, m0bb,
        m1aw, m1ab, m1bw, m1bb,
        w0w, w0b, w1w, w1b,
        g0wi, g0bi, gi0);

    gru_kernel<<<64, 64, 0, stream>>>(gi0, g0wh, g0bh, g1wi, g1wh, g1bi, g1bh, outw, outb, out);
}